// Round 1
// baseline (1215.234 us; speedup 1.0000x reference)
//
#include <hip/hip_runtime.h>
#include <hip/hip_bf16.h>
#include <cstdint>

typedef unsigned short u16;
typedef __attribute__((ext_vector_type(4))) float floatx4;
typedef __attribute__((ext_vector_type(8))) short shortx8;

#define G_STEP 8192
#define N_TOTAL 131072

__device__ __forceinline__ float bfu2f(u16 x){ return __uint_as_float(((unsigned)x)<<16); }
__device__ __forceinline__ u16 f2bfu(float x){ __hip_bfloat16 b = __float2bfloat16(x); return *reinterpret_cast<u16*>(&b); }
__device__ __forceinline__ float sigm(float x){ return 1.0f/(1.0f+__expf(-x)); }
__device__ __forceinline__ float tanh_(float x){
  float cx = fminf(fmaxf(x,-15.f),15.f);
  float e = __expf(2.f*cx);
  return (e-1.f)/(e+1.f);
}
__device__ __forceinline__ float invs(float x){ return 1.0f/sqrtf(x); }

// ---------------------------------------------------------------- prep
// convert weights f32 -> bf16 (layouts preserved), init sumsq[0..31]
__global__ __launch_bounds__(256) void prep_kernel(
    const float* __restrict__ una_W, const float* __restrict__ bin_W,
    const float* __restrict__ num_W2,
    u16* __restrict__ wbu, u16* __restrict__ wbb, u16* __restrict__ wbn,
    float* __restrict__ sumsq)
{
  int idx = blockIdx.x*256 + threadIdx.x;
  int stride = gridDim.x*256;
  for (int i = idx; i < 2*4*65536;  i += stride) wbu[i] = f2bfu(una_W[i]);
  for (int i = idx; i < 2*10*65536; i += stride) wbb[i] = f2bfu(bin_W[i]);
  for (int i = idx; i < 65536;      i += stride) wbn[i] = f2bfu(num_W2[i]);
  if (blockIdx.x == 0 && threadIdx.x < 32)
    sumsq[threadIdx.x] = ((threadIdx.x & 15) < 2) ? 1.0f : 0.0f;
}

// ---------------------------------------------------------------- step 0: leaves
// one wave per node; per-ROW norm, scale = min(1, 1/(nrm+1e-7))
__global__ __launch_bounds__(256) void leaf_kernel(
    const int* __restrict__ tokens, const float* __restrict__ leaf_table,
    u16* __restrict__ H, u16* __restrict__ C)
{
  int wave = threadIdx.x >> 6, lane = threadIdx.x & 63;
  int node = blockIdx.x*4 + wave;              // 0..8191
  int t = tokens[node];
  const float4 e4 = *reinterpret_cast<const float4*>(leaf_table + (size_t)t*256 + lane*4);
  float ss = e4.x*e4.x + e4.y*e4.y + e4.z*e4.z + e4.w*e4.w;
  #pragma unroll
  for (int o = 32; o; o >>= 1) ss += __shfl_down(ss, o);
  ss = __shfl(ss, 0);
  float scale = fminf(1.0f, 1.0f/(sqrtf(ss) + 1e-7f));
  ushort4 hv;
  hv.x = f2bfu(e4.x*scale); hv.y = f2bfu(e4.y*scale);
  hv.z = f2bfu(e4.z*scale); hv.w = f2bfu(e4.w*scale);
  ushort4 zv; zv.x = zv.y = zv.z = zv.w = 0;
  *reinterpret_cast<ushort4*>(H + (size_t)node*256 + lane*4) = hv;
  *reinterpret_cast<ushort4*>(C + (size_t)node*256 + lane*4) = zv;
}

// ---------------------------------------------------------------- step 1a: h1 = sigmoid(x*W1 + b1)
__global__ __launch_bounds__(256) void num_pre_kernel(
    const int* __restrict__ tokens, const float* __restrict__ W1,
    const float* __restrict__ b1, u16* __restrict__ h1)
{
  int flat = blockIdx.x*256 + threadIdx.x;     // 0..2M-1
  int n = flat >> 8, d = flat & 255;
  float x = (float)tokens[G_STEP + n];
  h1[flat] = f2bfu(sigm(x*W1[d] + b1[d]));
}

// ---------------------------------------------------------------- step 1b: e = sigmoid(g + b2)
__global__ __launch_bounds__(256) void gate_num_kernel(
    const u16* __restrict__ g, const float* __restrict__ b2,
    u16* __restrict__ H, u16* __restrict__ C)
{
  int flat = blockIdx.x*256 + threadIdx.x;
  int n = flat >> 8, j = flat & 255;
  float v = sigm(bfu2f(g[flat]) + b2[j]);
  size_t o = (size_t)(G_STEP + n)*256 + j;
  H[o] = f2bfu(v);
  C[o] = 0;
}

// ---------------------------------------------------------------- GEMM
// MODE 0: direct (numeric, A=h1, K=256, N=256)
// MODE 1: unary  (A=H[lidx], K=256, N=1024)
// MODE 2: binary (A=[H[lidx]|H[ridx]], K=512, N=1280)
// g[row][col] = sum_d A_norm[row][d] * W[sel][col&255][d]   (bf16 out)
// per-row h-scale folded into the epilogue (linear).
template<int MODE>
__global__ __launch_bounds__(256) void gemm_step(
    const u16* __restrict__ Asrc, const int* __restrict__ lidx,
    const int* __restrict__ ridx, const u16* __restrict__ Wb,
    const float* __restrict__ sumsq, u16* __restrict__ gout, int sbase)
{
  constexpr int NG   = (MODE==0) ? 1 : (MODE==1 ? 4 : 5);
  constexpr int NCOL = NG*256;
  const int lane = threadIdx.x & 63;
  const int wave = threadIdx.x >> 6;
  const int mbase = blockIdx.x*64 + wave*16;   // this wave's 16 rows
  const int nbase = blockIdx.y*128;
  const int l15 = lane & 15, kg = lane >> 4;

  int boff[8];
  #pragma unroll
  for (int c = 0; c < 8; c++){
    int col = nbase + c*16 + l15;
    int gate = col >> 8, e = col & 255;
    int w = (MODE==2) ? gate*2 : gate;
    boff[c] = (w*256 + e)*256 + kg*8;
  }

  int arow = mbase + l15;
  int rowL;
  if constexpr (MODE==0) rowL = arow; else rowL = lidx[sbase + arow];
  const u16* aL = Asrc + (size_t)rowL*256 + kg*8;

  floatx4 accL[8];
  #pragma unroll
  for (int c = 0; c < 8; c++) accL[c] = (floatx4)(0.0f);

  #pragma unroll
  for (int k0 = 0; k0 < 256; k0 += 32){
    shortx8 av = *reinterpret_cast<const shortx8*>(aL + k0);
    #pragma unroll
    for (int c = 0; c < 8; c++){
      shortx8 bv = *reinterpret_cast<const shortx8*>(Wb + boff[c] + k0);
      accL[c] = __builtin_amdgcn_mfma_f32_16x16x32_bf16(av, bv, accL[c], 0, 0, 0);
    }
  }

  floatx4 accR[(MODE==2) ? 8 : 1];
  if constexpr (MODE==2){
    #pragma unroll
    for (int c = 0; c < 8; c++) accR[c] = (floatx4)(0.0f);
    int rowR = ridx[sbase + arow];
    const u16* aR = Asrc + (size_t)rowR*256 + kg*8;
    #pragma unroll
    for (int k0 = 0; k0 < 256; k0 += 32){
      shortx8 av = *reinterpret_cast<const shortx8*>(aR + k0);
      #pragma unroll
      for (int c = 0; c < 8; c++){
        shortx8 bv = *reinterpret_cast<const shortx8*>(Wb + 65536 + boff[c] + k0);
        accR[c] = __builtin_amdgcn_mfma_f32_16x16x32_bf16(av, bv, accR[c], 0, 0, 0);
      }
    }
  }

  // epilogue: D layout col=lane&15, row=(lane>>4)*4+reg
  float sL[4], sR[4];
  #pragma unroll
  for (int r = 0; r < 4; r++){
    int orow = mbase + kg*4 + r;
    if constexpr (MODE==0){ sL[r] = 1.0f; (void)sR; }
    else {
      int ch = lidx[sbase + orow];
      sL[r] = invs(sumsq[ch >> 13]);
      if constexpr (MODE==2){
        int ch2 = ridx[sbase + orow];
        sR[r] = invs(sumsq[ch2 >> 13]);
      }
    }
  }
  #pragma unroll
  for (int c = 0; c < 8; c++){
    int col = nbase + c*16 + l15;
    #pragma unroll
    for (int r = 0; r < 4; r++){
      int orow = mbase + kg*4 + r;
      float v = accL[c][r]*sL[r];
      if constexpr (MODE==2) v += accR[c][r]*sR[r];
      gout[(size_t)orow*NCOL + col] = f2bfu(v);
    }
  }
}

// ---------------------------------------------------------------- gate cell (unary NG=4 / binary NG=5)
// reads g, computes c2,h2, stores unnormalized bf16, accumulates global sumsq
template<int NG>
__global__ __launch_bounds__(256) void gate_cell(
    const u16* __restrict__ g, const float* __restrict__ bias,
    const int* __restrict__ lidx, const int* __restrict__ ridx,
    const u16* __restrict__ Cin, float* __restrict__ sumsq,
    u16* __restrict__ H, u16* __restrict__ C, int sbase, int step)
{
  constexpr int NCOL = NG*256;
  __shared__ float sc[16];
  if (threadIdx.x < 16) sc[threadIdx.x] = invs(sumsq[16 + threadIdx.x]);
  __syncthreads();

  float accH = 0.f, accC = 0.f;
  int base = blockIdx.x*4096 + threadIdx.x;
  #pragma unroll
  for (int it = 0; it < 16; it++){
    int flat = base + it*256;
    int n = flat >> 8, j = flat & 255;
    int node = sbase + n;
    const u16* gr = g + (size_t)n*NCOL;
    float c2, h2;
    float i_ = sigm(bfu2f(gr[j]) + bias[j]);
    if constexpr (NG == 4){
      float f_ = sigm(bfu2f(gr[256+j]) + bias[256+j]);
      float o_ = sigm(bfu2f(gr[512+j]) + bias[512+j]);
      float u_ = tanh_(bfu2f(gr[768+j]) + bias[768+j]);
      int chl = lidx[node];
      float cl = bfu2f(Cin[(size_t)chl*256 + j]) * sc[chl >> 13];
      c2 = i_*u_ + f_*cl;
      h2 = o_*tanh_(c2);
    } else {
      float fl = sigm(bfu2f(gr[256+j])  + bias[256+j]);
      float fr = sigm(bfu2f(gr[512+j])  + bias[512+j]);
      float o_ = sigm(bfu2f(gr[768+j])  + bias[768+j]);
      float u_ = tanh_(bfu2f(gr[1024+j]) + bias[1024+j]);
      int chl = lidx[node], chr = ridx[node];
      float cl = bfu2f(Cin[(size_t)chl*256 + j]) * sc[chl >> 13];
      float cr = bfu2f(Cin[(size_t)chr*256 + j]) * sc[chr >> 13];
      c2 = i_*u_ + fl*cl + fr*cr;
      h2 = o_*tanh_(c2);
    }
    size_t o = (size_t)(sbase + n)*256 + j;
    H[o] = f2bfu(h2);
    C[o] = f2bfu(c2);
    accH += h2*h2;
    accC += c2*c2;
  }
  #pragma unroll
  for (int o = 32; o; o >>= 1){ accH += __shfl_down(accH, o); accC += __shfl_down(accC, o); }
  __shared__ float sh[8];
  int w = threadIdx.x >> 6;
  if ((threadIdx.x & 63) == 0){ sh[w] = accH; sh[4+w] = accC; }
  __syncthreads();
  if (threadIdx.x == 0)  atomicAdd(&sumsq[step],      sh[0]+sh[1]+sh[2]+sh[3]);
  if (threadIdx.x == 64) atomicAdd(&sumsq[16 + step], sh[4]+sh[5]+sh[6]+sh[7]);
}

// ---------------------------------------------------------------- output
__global__ __launch_bounds__(256) void out_kernel(
    const u16* __restrict__ H, const float* __restrict__ sumsq, float* __restrict__ out)
{
  size_t base = ((size_t)blockIdx.x*256 + threadIdx.x)*8;
  int n = (int)(base >> 8);
  float s = invs(sumsq[n >> 13]);
  const uint4 v = *reinterpret_cast<const uint4*>(H + base);
  float4 o0, o1;
  o0.x = bfu2f((u16)(v.x & 0xffff))*s; o0.y = bfu2f((u16)(v.x >> 16))*s;
  o0.z = bfu2f((u16)(v.y & 0xffff))*s; o0.w = bfu2f((u16)(v.y >> 16))*s;
  o1.x = bfu2f((u16)(v.z & 0xffff))*s; o1.y = bfu2f((u16)(v.z >> 16))*s;
  o1.z = bfu2f((u16)(v.w & 0xffff))*s; o1.w = bfu2f((u16)(v.w >> 16))*s;
  *reinterpret_cast<float4*>(out + base)     = o0;
  *reinterpret_cast<float4*>(out + base + 4) = o1;
}

// ---------------------------------------------------------------- host
extern "C" void kernel_launch(void* const* d_in, const int* in_sizes, int n_in,
                              void* d_out, int out_size, void* d_ws, size_t ws_size,
                              hipStream_t stream)
{
  const int*   tokens     = (const int*)d_in[0];
  const int*   lidx       = (const int*)d_in[1];
  const int*   ridx       = (const int*)d_in[2];
  const float* leaf_table = (const float*)d_in[6];
  const float* num_W1     = (const float*)d_in[7];
  const float* num_b1     = (const float*)d_in[8];
  const float* num_W2     = (const float*)d_in[9];
  const float* num_b2     = (const float*)d_in[10];
  const float* una_W      = (const float*)d_in[11];
  const float* una_b      = (const float*)d_in[12];
  const float* bin_W      = (const float*)d_in[13];
  const float* bin_b      = (const float*)d_in[14];

  // ws layout: H | wbu | wbb | wbn | h1 | sumsq   (~75.1 MB)
  char* ws = (char*)d_ws;
  size_t off = 0;
  u16* H   = (u16*)(ws + off); off += (size_t)N_TOTAL*256*2;
  u16* wbu = (u16*)(ws + off); off += (size_t)2*4*65536*2;
  u16* wbb = (u16*)(ws + off); off += (size_t)2*10*65536*2;
  u16* wbn = (u16*)(ws + off); off += (size_t)65536*2;
  u16* h1  = (u16*)(ws + off); off += (size_t)G_STEP*256*2;
  float* sumsq = (float*)(ws + off); off += 32*4;

  // C (67 MB) and g scratch (<=21 MB) live in d_out; out_kernel overwrites at the end
  u16* C = (u16*)d_out;
  u16* g = (u16*)((char*)d_out + (size_t)N_TOTAL*256*2);

  prep_kernel<<<1024, 256, 0, stream>>>(una_W, bin_W, num_W2, wbu, wbb, wbn, sumsq);
  leaf_kernel<<<G_STEP/4, 256, 0, stream>>>(tokens, leaf_table, H, C);
  num_pre_kernel<<<G_STEP, 256, 0, stream>>>(tokens, num_W1, num_b1, h1);
  gemm_step<0><<<dim3(128, 2), 256, 0, stream>>>(h1, nullptr, nullptr, wbn, sumsq, g, 0);
  gate_num_kernel<<<G_STEP, 256, 0, stream>>>(g, num_b2, H, C);

  const int sched[16] = {-1,-2,0,2,1,3,0,2,1,3,0,2,1,3,0,2};
  for (int d = 2; d < 16; d++){
    int op = sched[d];
    int sbase = d*G_STEP;
    if (op == 0 || op == 1){
      gemm_step<1><<<dim3(128, 8), 256, 0, stream>>>(
          H, lidx, nullptr, wbu + (size_t)op*4*65536, sumsq, g, sbase);
      gate_cell<4><<<512, 256, 0, stream>>>(
          g, una_b + (size_t)op*4*256, lidx, nullptr, C, sumsq, H, C, sbase, d);
    } else {
      int o2 = op - 2;
      gemm_step<2><<<dim3(128, 10), 256, 0, stream>>>(
          H, lidx, ridx, wbb + (size_t)o2*10*65536, sumsq, g, sbase);
      gate_cell<5><<<512, 256, 0, stream>>>(
          g, bin_b + (size_t)o2*5*256, lidx, ridx, C, sumsq, H, C, sbase, d);
    }
  }
  out_kernel<<<(N_TOTAL*256)/(256*8), 256, 0, stream>>>(H, sumsq, (float*)d_out);
}

// Round 2
// 534.518 us; speedup vs baseline: 2.2735x; 2.2735x over previous
//
#include <hip/hip_runtime.h>
#include <hip/hip_bf16.h>
#include <cstdint>

typedef unsigned short u16;
typedef unsigned int u32;
typedef __attribute__((ext_vector_type(4))) float floatx4;
typedef __attribute__((ext_vector_type(8))) short shortx8;

#define G_STEP 8192
#define N_TOTAL 131072

__device__ __forceinline__ float bfu2f(u16 x){ return __uint_as_float(((unsigned)x)<<16); }
__device__ __forceinline__ u16 f2bfu(float x){ __hip_bfloat16 b = __float2bfloat16(x); return *reinterpret_cast<u16*>(&b); }
__device__ __forceinline__ float sigm(float x){ return 1.0f/(1.0f+__expf(-x)); }
__device__ __forceinline__ float tanh_(float x){
  float cx = fminf(fmaxf(x,-15.f),15.f);
  float e = __expf(2.f*cx);
  return (e-1.f)/(e+1.f);
}
__device__ __forceinline__ float invs(float x){ return 1.0f/sqrtf(x); }

// async global->LDS 16B: LDS dest is wave-uniform base + lane*16
__device__ __forceinline__ void gl16(const void* g, void* l){
  __builtin_amdgcn_global_load_lds((const __attribute__((address_space(1))) u32*)g,
                                   (__attribute__((address_space(3))) u32*)l, 16, 0, 0);
}

// ---------------------------------------------------------------- prep
__global__ __launch_bounds__(256) void prep_kernel(
    const float* __restrict__ una_W, const float* __restrict__ bin_W,
    const float* __restrict__ num_W2,
    u16* __restrict__ wbu, u16* __restrict__ wbb, u16* __restrict__ wbn,
    float* __restrict__ sumsq)
{
  int idx = blockIdx.x*256 + threadIdx.x;
  int stride = gridDim.x*256;
  for (int i = idx; i < 2*4*65536;  i += stride) wbu[i] = f2bfu(una_W[i]);
  for (int i = idx; i < 2*10*65536; i += stride) wbb[i] = f2bfu(bin_W[i]);
  for (int i = idx; i < 65536;      i += stride) wbn[i] = f2bfu(num_W2[i]);
  if (blockIdx.x == 0 && threadIdx.x < 32)
    sumsq[threadIdx.x] = ((threadIdx.x & 15) < 2) ? 1.0f : 0.0f;
}

// ---------------------------------------------------------------- step 0: leaves (per-row norm)
__global__ __launch_bounds__(256) void leaf_kernel(
    const int* __restrict__ tokens, const float* __restrict__ leaf_table,
    u16* __restrict__ H, u16* __restrict__ C)
{
  int wave = threadIdx.x >> 6, lane = threadIdx.x & 63;
  int node = blockIdx.x*4 + wave;
  int t = tokens[node];
  const float4 e4 = *reinterpret_cast<const float4*>(leaf_table + (size_t)t*256 + lane*4);
  float ss = e4.x*e4.x + e4.y*e4.y + e4.z*e4.z + e4.w*e4.w;
  #pragma unroll
  for (int o = 32; o; o >>= 1) ss += __shfl_down(ss, o);
  ss = __shfl(ss, 0);
  float scale = fminf(1.0f, 1.0f/(sqrtf(ss) + 1e-7f));
  ushort4 hv;
  hv.x = f2bfu(e4.x*scale); hv.y = f2bfu(e4.y*scale);
  hv.z = f2bfu(e4.z*scale); hv.w = f2bfu(e4.w*scale);
  ushort4 zv; zv.x = zv.y = zv.z = zv.w = 0;
  *reinterpret_cast<ushort4*>(H + (size_t)node*256 + lane*4) = hv;
  *reinterpret_cast<ushort4*>(C + (size_t)node*256 + lane*4) = zv;
}

// ---------------------------------------------------------------- step 1a
__global__ __launch_bounds__(256) void num_pre_kernel(
    const int* __restrict__ tokens, const float* __restrict__ W1,
    const float* __restrict__ b1, u16* __restrict__ h1)
{
  int flat = blockIdx.x*256 + threadIdx.x;
  int n = flat >> 8, d = flat & 255;
  float x = (float)tokens[G_STEP + n];
  h1[flat] = f2bfu(sigm(x*W1[d] + b1[d]));
}

// ---------------------------------------------------------------- step 1b
__global__ __launch_bounds__(256) void gate_num_kernel(
    const u16* __restrict__ g, const float* __restrict__ b2,
    u16* __restrict__ H, u16* __restrict__ C)
{
  int flat = blockIdx.x*256 + threadIdx.x;
  int n = flat >> 8, j = flat & 255;
  float v = sigm(bfu2f(g[flat]) + b2[j]);
  size_t o = (size_t)(G_STEP + n)*256 + j;
  H[o] = f2bfu(v);
  C[o] = 0;
}

// ---------------------------------------------------------------- GEMM v2 (LDS double-buffered, MFMA)
// MODE 0: A=h1 identity rows, K=256, N=256
// MODE 1: A=H[lidx],         K=256, N=1024
// MODE 2: A=[H[lidx]|H[ridx]] concat-K, K=512, N=1280
// Tile 128x128, BK=64, 4 waves each 64x64.  LDS rows hold 8x16B chunks,
// XOR-swizzled (chunk ^ row&7) via pre-swizzled global source (rule #21).
template<int MODE>
__global__ __launch_bounds__(256, 2) void gemm2(
    const u16* __restrict__ Asrc, const int* __restrict__ lidx,
    const int* __restrict__ ridx, const u16* __restrict__ Wb,
    u16* __restrict__ gout, int sbase)
{
  constexpr int NG   = (MODE==0) ? 1 : (MODE==1 ? 4 : 5);
  constexpr int NCOL = NG*256;
  constexpr int NT   = (MODE==2) ? 8 : 4;   // K-steps of 64
  __shared__ u16 S[2][2][128][64];          // [buf][A/B][row][k]  = 64 KB

  const int tid  = threadIdx.x;
  const int lane = tid & 63, wave = tid >> 6;
  const int mbase = blockIdx.x*128, nbase = blockIdx.y*128;
  const int l15 = lane & 15, kg = lane >> 4;
  const int rhi = lane >> 3;               // row-within-8 for staging
  const int lc  = (lane & 7) ^ rhi;        // pre-swizzled logical 16B chunk

  // per-thread staging source pointers (4 rounds of 32 rows; this thread's row)
  const u16* aL[4]; const u16* aR[4]; const u16* bB[4];
  const int gsel = nbase >> 8;
  const int e0   = nbase & 255;
  const int wsel = (MODE==2) ? 2*gsel : gsel;
  #pragma unroll
  for (int rr = 0; rr < 4; rr++){
    int r = rr*32 + wave*8 + rhi;
    int gr;
    if constexpr (MODE==0) gr = mbase + r;
    else                   gr = lidx[sbase + mbase + r];
    aL[rr] = Asrc + (size_t)gr*256 + lc*8;
    if constexpr (MODE==2)
      aR[rr] = Asrc + (size_t)ridx[sbase + mbase + r]*256 + lc*8;
    bB[rr] = Wb + (size_t)(wsel*256 + e0 + r)*256 + lc*8;
  }

  floatx4 acc[4][4];
  #pragma unroll
  for (int i = 0; i < 4; i++)
    #pragma unroll
    for (int j = 0; j < 4; j++) acc[i][j] = (floatx4)(0.0f);

  const int wm = (wave >> 1)*64, wn = (wave & 1)*64;

  auto stage = [&](int t, int buf){
    const int kk = t*64;
    #pragma unroll
    for (int rr = 0; rr < 4; rr++){
      const u16 *ga, *gb;
      if constexpr (MODE==2){
        if (kk >= 256){ ga = aR[rr] + (kk-256); gb = bB[rr] + 65536 + (kk-256); }
        else          { ga = aL[rr] + kk;       gb = bB[rr] + kk; }
      } else { ga = aL[rr] + kk; gb = bB[rr] + kk; }
      gl16(ga, &S[buf][0][rr*32 + wave*8][0]);
      gl16(gb, &S[buf][1][rr*32 + wave*8][0]);
    }
  };

  stage(0, 0);
  __syncthreads();

  #pragma unroll
  for (int t = 0; t < NT; t++){
    if (t+1 < NT) stage(t+1, (t+1)&1);
    const int buf = t & 1;
    #pragma unroll
    for (int j = 0; j < 2; j++){
      shortx8 af[4], bfr[4];
      const int pc = ((j*4 + kg) ^ (l15 & 7)) * 8;
      #pragma unroll
      for (int i = 0; i < 4; i++){
        af[i]  = *reinterpret_cast<const shortx8*>(&S[buf][0][wm + i*16 + l15][pc]);
        bfr[i] = *reinterpret_cast<const shortx8*>(&S[buf][1][wn + i*16 + l15][pc]);
      }
      #pragma unroll
      for (int mi = 0; mi < 4; mi++)
        #pragma unroll
        for (int ni = 0; ni < 4; ni++)
          acc[mi][ni] = __builtin_amdgcn_mfma_f32_16x16x32_bf16(af[mi], bfr[ni], acc[mi][ni], 0, 0, 0);
    }
    __syncthreads();
  }

  // epilogue: D layout col=lane&15, row=(lane>>4)*4+reg
  #pragma unroll
  for (int mi = 0; mi < 4; mi++){
    #pragma unroll
    for (int r = 0; r < 4; r++){
      int orow = mbase + wm + mi*16 + kg*4 + r;
      u16* op = gout + (size_t)orow*NCOL + nbase + wn + l15;
      #pragma unroll
      for (int ni = 0; ni < 4; ni++)
        op[ni*16] = f2bfu(acc[mi][ni][r]);
    }
  }
}

// ---------------------------------------------------------------- gate cell
template<int NGATE>
__global__ __launch_bounds__(256) void gate_cell(
    const u16* __restrict__ g, const float* __restrict__ bias,
    const int* __restrict__ lidx, const int* __restrict__ ridx,
    const u16* __restrict__ Cin, float* __restrict__ sumsq,
    u16* __restrict__ H, u16* __restrict__ C, int sbase, int step)
{
  constexpr int NCOL = NGATE*256;
  __shared__ float sc[16];
  if (threadIdx.x < 16) sc[threadIdx.x] = invs(sumsq[16 + threadIdx.x]);
  __syncthreads();

  float accH = 0.f, accC = 0.f;
  int base = blockIdx.x*4096 + threadIdx.x;
  #pragma unroll
  for (int it = 0; it < 16; it++){
    int flat = base + it*256;
    int n = flat >> 8, j = flat & 255;
    int node = sbase + n;
    const u16* gr = g + (size_t)n*NCOL;
    float c2, h2;
    float i_ = sigm(bfu2f(gr[j]) + bias[j]);
    if constexpr (NGATE == 4){
      float f_ = sigm(bfu2f(gr[256+j]) + bias[256+j]);
      float o_ = sigm(bfu2f(gr[512+j]) + bias[512+j]);
      float u_ = tanh_(bfu2f(gr[768+j]) + bias[768+j]);
      int chl = lidx[node];
      float cl = bfu2f(Cin[(size_t)chl*256 + j]) * sc[chl >> 13];
      c2 = i_*u_ + f_*cl;
      h2 = o_*tanh_(c2);
    } else {
      float fl = sigm(bfu2f(gr[256+j])  + bias[256+j]);
      float fr = sigm(bfu2f(gr[512+j])  + bias[512+j]);
      float o_ = sigm(bfu2f(gr[768+j])  + bias[768+j]);
      float u_ = tanh_(bfu2f(gr[1024+j]) + bias[1024+j]);
      int chl = lidx[node], chr = ridx[node];
      float cl = bfu2f(Cin[(size_t)chl*256 + j]) * sc[chl >> 13];
      float cr = bfu2f(Cin[(size_t)chr*256 + j]) * sc[chr >> 13];
      c2 = i_*u_ + fl*cl + fr*cr;
      h2 = o_*tanh_(c2);
    }
    size_t o = (size_t)(sbase + n)*256 + j;
    H[o] = f2bfu(h2);
    C[o] = f2bfu(c2);
    accH += h2*h2;
    accC += c2*c2;
  }
  #pragma unroll
  for (int o = 32; o; o >>= 1){ accH += __shfl_down(accH, o); accC += __shfl_down(accC, o); }
  __shared__ float sh[8];
  int w = threadIdx.x >> 6;
  if ((threadIdx.x & 63) == 0){ sh[w] = accH; sh[4+w] = accC; }
  __syncthreads();
  if (threadIdx.x == 0)  atomicAdd(&sumsq[step],      sh[0]+sh[1]+sh[2]+sh[3]);
  if (threadIdx.x == 64) atomicAdd(&sumsq[16 + step], sh[4]+sh[5]+sh[6]+sh[7]);
}

// ---------------------------------------------------------------- normalize H of one step in place
__global__ __launch_bounds__(256) void norm_h_kernel(
    u16* __restrict__ H, const float* __restrict__ sumsq, int step)
{
  float s = invs(sumsq[step]);
  size_t base = (size_t)step*G_STEP*256 + ((size_t)blockIdx.x*256 + threadIdx.x)*8;
  uint4 v = *reinterpret_cast<const uint4*>(H + base);
  uint4 o;
  #define MUL2(p) ( (u32)f2bfu(bfu2f((u16)((p)&0xffff))*s) | ((u32)f2bfu(bfu2f((u16)((p)>>16))*s) << 16) )
  o.x = MUL2(v.x); o.y = MUL2(v.y); o.z = MUL2(v.z); o.w = MUL2(v.w);
  #undef MUL2
  *reinterpret_cast<uint4*>(H + base) = o;
}

// ---------------------------------------------------------------- output: plain bf16->f32 convert
__global__ __launch_bounds__(256) void out_kernel(
    const u16* __restrict__ H, float* __restrict__ out)
{
  size_t base = ((size_t)blockIdx.x*256 + threadIdx.x)*8;
  const uint4 v = *reinterpret_cast<const uint4*>(H + base);
  float4 o0, o1;
  o0.x = bfu2f((u16)(v.x & 0xffff)); o0.y = bfu2f((u16)(v.x >> 16));
  o0.z = bfu2f((u16)(v.y & 0xffff)); o0.w = bfu2f((u16)(v.y >> 16));
  o1.x = bfu2f((u16)(v.z & 0xffff)); o1.y = bfu2f((u16)(v.z >> 16));
  o1.z = bfu2f((u16)(v.w & 0xffff)); o1.w = bfu2f((u16)(v.w >> 16));
  *reinterpret_cast<float4*>(out + base)     = o0;
  *reinterpret_cast<float4*>(out + base + 4) = o1;
}

// ---------------------------------------------------------------- host
extern "C" void kernel_launch(void* const* d_in, const int* in_sizes, int n_in,
                              void* d_out, int out_size, void* d_ws, size_t ws_size,
                              hipStream_t stream)
{
  const int*   tokens     = (const int*)d_in[0];
  const int*   lidx       = (const int*)d_in[1];
  const int*   ridx       = (const int*)d_in[2];
  const float* leaf_table = (const float*)d_in[6];
  const float* num_W1     = (const float*)d_in[7];
  const float* num_b1     = (const float*)d_in[8];
  const float* num_W2     = (const float*)d_in[9];
  const float* num_b2     = (const float*)d_in[10];
  const float* una_b      = (const float*)d_in[12];
  const float* una_W      = (const float*)d_in[11];
  const float* bin_W      = (const float*)d_in[13];
  const float* bin_b      = (const float*)d_in[14];

  // ws layout: H | wbu | wbb | wbn | h1 | sumsq   (~75.1 MB)
  char* ws = (char*)d_ws;
  size_t off = 0;
  u16* H   = (u16*)(ws + off); off += (size_t)N_TOTAL*256*2;
  u16* wbu = (u16*)(ws + off); off += (size_t)2*4*65536*2;
  u16* wbb = (u16*)(ws + off); off += (size_t)2*10*65536*2;
  u16* wbn = (u16*)(ws + off); off += (size_t)65536*2;
  u16* h1  = (u16*)(ws + off); off += (size_t)G_STEP*256*2;
  float* sumsq = (float*)(ws + off); off += 32*4;

  // C (67 MB) and g scratch (<=21 MB) live in d_out; out_kernel overwrites at the end
  u16* C = (u16*)d_out;
  u16* g = (u16*)((char*)d_out + (size_t)N_TOTAL*256*2);

  prep_kernel<<<1024, 256, 0, stream>>>(una_W, bin_W, num_W2, wbu, wbb, wbn, sumsq);
  leaf_kernel<<<G_STEP/4, 256, 0, stream>>>(tokens, leaf_table, H, C);
  num_pre_kernel<<<G_STEP, 256, 0, stream>>>(tokens, num_W1, num_b1, h1);
  gemm2<0><<<dim3(64, 2), 256, 0, stream>>>(h1, nullptr, nullptr, wbn, g, 0);
  gate_num_kernel<<<G_STEP, 256, 0, stream>>>(g, num_b2, H, C);

  const int sched[16] = {-1,-2,0,2,1,3,0,2,1,3,0,2,1,3,0,2};
  for (int d = 2; d < 16; d++){
    int op = sched[d];
    int sbase = d*G_STEP;
    if (op == 0 || op == 1){
      gemm2<1><<<dim3(64, 8), 256, 0, stream>>>(
          H, lidx, nullptr, wbu + (size_t)op*4*65536, g, sbase);
      gate_cell<4><<<512, 256, 0, stream>>>(
          g, una_b + (size_t)op*4*256, lidx, nullptr, C, sumsq, H, C, sbase, d);
    } else {
      int o2 = op - 2;
      gemm2<2><<<dim3(64, 10), 256, 0, stream>>>(
          H, lidx, ridx, wbb + (size_t)o2*10*65536, g, sbase);
      gate_cell<5><<<512, 256, 0, stream>>>(
          g, bin_b + (size_t)o2*5*256, lidx, ridx, C, sumsq, H, C, sbase, d);
    }
    norm_h_kernel<<<1024, 256, 0, stream>>>(H, sumsq, d);
  }
  out_kernel<<<(N_TOTAL*256)/(256*8), 256, 0, stream>>>(H, (float*)d_out);
}

// Round 3
// 399.866 us; speedup vs baseline: 3.0391x; 1.3367x over previous
//
#include <hip/hip_runtime.h>
#include <hip/hip_bf16.h>
#include <cstdint>

typedef unsigned short u16;
typedef unsigned int u32;
typedef __attribute__((ext_vector_type(4))) float floatx4;
typedef __attribute__((ext_vector_type(8))) short shortx8;

#define G_STEP 8192
#define N_TOTAL 131072
#define RHALF (1280*256)

__device__ __forceinline__ float bfu2f(u16 x){ return __uint_as_float(((unsigned)x)<<16); }
__device__ __forceinline__ u16 f2bfu(float x){ __hip_bfloat16 b = __float2bfloat16(x); return *reinterpret_cast<u16*>(&b); }
__device__ __forceinline__ float sigm(float x){ return 1.0f/(1.0f+__expf(-x)); }
__device__ __forceinline__ float tanh_(float x){
  float cx = fminf(fmaxf(x,-15.f),15.f);
  float e = __expf(2.f*cx);
  return (e-1.f)/(e+1.f);
}
__device__ __forceinline__ float invs(float x){ return 1.0f/sqrtf(x); }

__device__ __forceinline__ void gl16(const void* g, void* l){
  __builtin_amdgcn_global_load_lds((const __attribute__((address_space(1))) u32*)g,
                                   (__attribute__((address_space(3))) u32*)l, 16, 0, 0);
}

__device__ __forceinline__ void cvt8(const float* __restrict__ src, u16* __restrict__ dst){
  float4 a = *reinterpret_cast<const float4*>(src);
  float4 b = *reinterpret_cast<const float4*>(src+4);
  ushort4 o0; o0.x=f2bfu(a.x); o0.y=f2bfu(a.y); o0.z=f2bfu(a.z); o0.w=f2bfu(a.w);
  ushort4 o1; o1.x=f2bfu(b.x); o1.y=f2bfu(b.y); o1.z=f2bfu(b.z); o1.w=f2bfu(b.w);
  *reinterpret_cast<ushort4*>(dst)   = o0;
  *reinterpret_cast<ushort4*>(dst+4) = o1;
}

// ---------------------------------------------------------------- setup (fused prep + leaf + num_pre + sumsq init)
// Weight layouts (bf16):
//  wbu[op][eblk(16)][gate(4)][el(16)][d]   rows = op*1024 + eblk*64 + gate*16 + el
//  wbb[ob][lr(2)][eblk(16)][gate(5)][el(16)][d] rows = ((ob*2+lr)*1280) + eblk*80 + gate*16 + el
//  wbn[e][d] plain
__global__ __launch_bounds__(256) void setup_kernel(
    const int* __restrict__ tokens, const float* __restrict__ leaf_table,
    const float* __restrict__ W1, const float* __restrict__ b1,
    const float* __restrict__ una_W, const float* __restrict__ bin_W,
    const float* __restrict__ num_W2,
    u16* __restrict__ wbu, u16* __restrict__ wbb, u16* __restrict__ wbn,
    u16* __restrict__ h1, u16* __restrict__ H, u16* __restrict__ C,
    float* __restrict__ sumsq)
{
  const int b = blockIdx.x, tid = threadIdx.x;
  if (b < 256){                                  // wbu: 2048 rows
    int row = b*8 + (tid>>5), d0 = (tid&31)*8;
    int op = row>>10, w = row&1023;
    int gate = (w>>4)&3, e = ((w>>6)<<4) | (w&15);
    cvt8(una_W + (size_t)((op*4+gate)*256 + e)*256 + d0, wbu + (size_t)row*256 + d0);
  } else if (b < 896){                           // wbb: 5120 rows
    int row = (b-256)*8 + (tid>>5), d0 = (tid&31)*8;
    int ob = row / 2560, rem = row - ob*2560;
    int lr = rem / 1280, rw = rem - lr*1280;
    int eblk = rw / 80, rem2 = rw - eblk*80;
    int gate = rem2 >> 4, el = rem2 & 15;
    int e = eblk*16 + el;
    cvt8(bin_W + (size_t)((ob*10 + 2*gate + lr)*256 + e)*256 + d0, wbb + (size_t)row*256 + d0);
  } else if (b < 928){                           // wbn: 256 rows plain
    int row = (b-896)*8 + (tid>>5), d0 = (tid&31)*8;
    cvt8(num_W2 + (size_t)row*256 + d0, wbn + (size_t)row*256 + d0);
  } else if (b < 2976){                          // leaf: 8192 nodes, 4/block
    int wave = tid >> 6, lane = tid & 63;
    int node = (b-928)*4 + wave;
    int t = tokens[node];
    const float4 e4 = *reinterpret_cast<const float4*>(leaf_table + (size_t)t*256 + lane*4);
    float ss = e4.x*e4.x + e4.y*e4.y + e4.z*e4.z + e4.w*e4.w;
    #pragma unroll
    for (int o = 32; o; o >>= 1) ss += __shfl_down(ss, o);
    ss = __shfl(ss, 0);
    float scale = fminf(1.0f, 1.0f/(sqrtf(ss) + 1e-7f));
    ushort4 hv;
    hv.x = f2bfu(e4.x*scale); hv.y = f2bfu(e4.y*scale);
    hv.z = f2bfu(e4.z*scale); hv.w = f2bfu(e4.w*scale);
    ushort4 zv; zv.x = zv.y = zv.z = zv.w = 0;
    *reinterpret_cast<ushort4*>(H + (size_t)node*256 + lane*4) = hv;
    *reinterpret_cast<ushort4*>(C + (size_t)node*256 + lane*4) = zv;
  } else if (b < 4000){                          // num_pre: 2M elems, 8/thread
    int flat = (b-2976)*2048 + tid*8;
    int n = flat >> 8, d0 = flat & 255;
    float x = (float)tokens[G_STEP + n];
    float4 w0 = *reinterpret_cast<const float4*>(W1 + d0);
    float4 w1 = *reinterpret_cast<const float4*>(W1 + d0 + 4);
    float4 c0 = *reinterpret_cast<const float4*>(b1 + d0);
    float4 c1 = *reinterpret_cast<const float4*>(b1 + d0 + 4);
    ushort4 o0, o1;
    o0.x = f2bfu(sigm(x*w0.x + c0.x)); o0.y = f2bfu(sigm(x*w0.y + c0.y));
    o0.z = f2bfu(sigm(x*w0.z + c0.z)); o0.w = f2bfu(sigm(x*w0.w + c0.w));
    o1.x = f2bfu(sigm(x*w1.x + c1.x)); o1.y = f2bfu(sigm(x*w1.y + c1.y));
    o1.z = f2bfu(sigm(x*w1.z + c1.z)); o1.w = f2bfu(sigm(x*w1.w + c1.w));
    *reinterpret_cast<ushort4*>(h1 + flat)     = o0;
    *reinterpret_cast<ushort4*>(h1 + flat + 4) = o1;
  } else {                                       // sumsq init
    if (tid < 32) sumsq[tid] = ((tid & 15) < 2) ? 1.0f : 0.0f;
  }
}

// ---------------------------------------------------------------- fused GEMM + LSTM cell
// MODE 0: numeric  A=h1 (rows direct), K=256, cols=256 plain,   epi: H=sigm(g+b2), C=0
// MODE 1: unary    A=H[lidx],          K=256, cols=1024 fused,  epi: 4-gate cell
// MODE 2: binary   A=[H[l]|H[r]] K=512 concat, cols=1280 fused, epi: 5-gate cell
// Tile 128 x (128 | 160).  4 waves 2x2.  LDS dbuf, XOR-swizzled chunks.
template<int MODE>
__global__ __launch_bounds__(256, 2) void gemm_fused(
    const u16* __restrict__ Asrc, const int* __restrict__ lidx,
    const int* __restrict__ ridx, const u16* __restrict__ Wb,
    const float* __restrict__ bias, const u16* __restrict__ Cin,
    float* __restrict__ sumsq, u16* __restrict__ H, u16* __restrict__ C,
    int sbase, int step)
{
  constexpr int NG  = (MODE==0) ? 1 : (MODE==1 ? 4 : 5);
  constexpr int NBR = (MODE==2) ? 160 : 128;   // B tile rows (= out cols)
  constexpr int NT  = (MODE==2) ? 8 : 4;       // K-steps of 64
  constexpr int BR  = NBR/32;                  // B staging rounds
  constexpr int WN  = (MODE==2) ? 80 : 64;     // wave col extent
  constexpr int NFR = WN/16;                   // B frags per wave

  __shared__ u16 SA[2][128][64];
  __shared__ u16 SB[2][NBR][64];
  __shared__ float scC[16];
  __shared__ float red[8];

  const int tid  = threadIdx.x;
  const int lane = tid & 63, wave = tid >> 6;
  const int mbase = blockIdx.x*128;
  const int nbase = blockIdx.y*NBR;
  const int l15 = lane & 15, kg = lane >> 4;
  const int rhi = lane >> 3;
  const int lc  = (lane & 7) ^ rhi;

  if (MODE != 0 && tid < 16) scC[tid] = invs(sumsq[16 + tid]);

  const u16* aL[4]; const u16* aR[4]; const u16* bP[BR];
  #pragma unroll
  for (int rr = 0; rr < 4; rr++){
    int r = rr*32 + wave*8 + rhi;
    int gr;
    if constexpr (MODE==0) gr = mbase + r;
    else                   gr = lidx[sbase + mbase + r];
    aL[rr] = Asrc + (size_t)gr*256 + lc*8;
    if constexpr (MODE==2)
      aR[rr] = Asrc + (size_t)ridx[sbase + mbase + r]*256 + lc*8;
  }
  #pragma unroll
  for (int rb = 0; rb < BR; rb++){
    int r = rb*32 + wave*8 + rhi;
    bP[rb] = Wb + (size_t)(nbase + r)*256 + lc*8;
  }

  floatx4 acc[4][NFR];
  #pragma unroll
  for (int i = 0; i < 4; i++)
    #pragma unroll
    for (int j = 0; j < NFR; j++) acc[i][j] = (floatx4)(0.0f);

  const int wm = (wave >> 1)*64, wn = (wave & 1)*WN;

  auto stage = [&](int t, int buf){
    const int kk = t*64;
    #pragma unroll
    for (int rr = 0; rr < 4; rr++){
      const u16* ga;
      if constexpr (MODE==2){ ga = (kk >= 256) ? aR[rr] + (kk-256) : aL[rr] + kk; }
      else                  { ga = aL[rr] + kk; }
      gl16(ga, &SA[buf][rr*32 + wave*8][0]);
    }
    #pragma unroll
    for (int rb = 0; rb < BR; rb++){
      const u16* gb;
      if constexpr (MODE==2){ gb = (kk >= 256) ? bP[rb] + RHALF + (kk-256) : bP[rb] + kk; }
      else                  { gb = bP[rb] + kk; }
      gl16(gb, &SB[buf][rb*32 + wave*8][0]);
    }
  };

  stage(0, 0);
  __syncthreads();

  #pragma unroll
  for (int t = 0; t < NT; t++){
    if (t+1 < NT) stage(t+1, (t+1)&1);
    const int buf = t & 1;
    #pragma unroll
    for (int j = 0; j < 2; j++){
      shortx8 af[4], bfr[NFR];
      const int pc = ((j*4 + kg) ^ (l15 & 7)) * 8;
      #pragma unroll
      for (int i = 0; i < 4; i++)
        af[i] = *reinterpret_cast<const shortx8*>(&SA[buf][wm + i*16 + l15][pc]);
      #pragma unroll
      for (int n = 0; n < NFR; n++)
        bfr[n] = *reinterpret_cast<const shortx8*>(&SB[buf][wn + n*16 + l15][pc]);
      #pragma unroll
      for (int mi = 0; mi < 4; mi++)
        #pragma unroll
        for (int ni = 0; ni < NFR; ni++)
          acc[mi][ni] = __builtin_amdgcn_mfma_f32_16x16x32_bf16(af[mi], bfr[ni], acc[mi][ni], 0, 0, 0);
    }
    __syncthreads();
  }

  // ---------------- fused epilogue ----------------
  if constexpr (MODE == 0){
    float bb[4];
    #pragma unroll
    for (int ni = 0; ni < 4; ni++) bb[ni] = bias[nbase + wn + ni*16 + l15];
    #pragma unroll
    for (int mi = 0; mi < 4; mi++){
      #pragma unroll
      for (int r = 0; r < 4; r++){
        int node = sbase + mbase + wm + mi*16 + kg*4 + r;
        u16* hp = H + (size_t)node*256 + nbase + wn + l15;
        u16* cp = C + (size_t)node*256 + nbase + wn + l15;
        #pragma unroll
        for (int ni = 0; ni < 4; ni++){
          hp[ni*16] = f2bfu(sigm(acc[mi][ni][r] + bb[ni]));
          cp[ni*16] = 0;
        }
      }
    }
  } else {
    const int eb = blockIdx.y*2 + (wave & 1);
    const int e  = eb*16 + l15;
    float bb[NG];
    #pragma unroll
    for (int g = 0; g < NG; g++) bb[g] = bias[g*256 + e];
    float hss = 0.f, css = 0.f;
    #pragma unroll
    for (int mi = 0; mi < 4; mi++){
      #pragma unroll
      for (int r = 0; r < 4; r++){
        int orow = mbase + wm + mi*16 + kg*4 + r;
        int node = sbase + orow;
        int chl = lidx[node];
        float cl = bfu2f(Cin[(size_t)chl*256 + e]) * scC[chl >> 13];
        float c2, h2;
        if constexpr (MODE == 1){
          float i_ = sigm(acc[mi][0][r] + bb[0]);
          float f_ = sigm(acc[mi][1][r] + bb[1]);
          float o_ = sigm(acc[mi][2][r] + bb[2]);
          float u_ = tanh_(acc[mi][3][r] + bb[3]);
          c2 = i_*u_ + f_*cl;
          h2 = o_*tanh_(c2);
        } else {
          int chr = ridx[node];
          float cr = bfu2f(Cin[(size_t)chr*256 + e]) * scC[chr >> 13];
          float i_ = sigm(acc[mi][0][r] + bb[0]);
          float fl = sigm(acc[mi][1][r] + bb[1]);
          float fr = sigm(acc[mi][2][r] + bb[2]);
          float o_ = sigm(acc[mi][3][r] + bb[3]);
          float u_ = tanh_(acc[mi][4][r] + bb[4]);
          c2 = i_*u_ + fl*cl + fr*cr;
          h2 = o_*tanh_(c2);
        }
        H[(size_t)node*256 + e] = f2bfu(h2);
        C[(size_t)node*256 + e] = f2bfu(c2);
        hss += h2*h2;
        css += c2*c2;
      }
    }
    #pragma unroll
    for (int o = 32; o; o >>= 1){ hss += __shfl_down(hss, o); css += __shfl_down(css, o); }
    if (lane == 0){ red[wave] = hss; red[4+wave] = css; }
    __syncthreads();
    if (tid == 0)  atomicAdd(&sumsq[step],      red[0]+red[1]+red[2]+red[3]);
    if (tid == 64) atomicAdd(&sumsq[16 + step], red[4]+red[5]+red[6]+red[7]);
  }
}

// ---------------------------------------------------------------- normalize H of one step in place
__global__ __launch_bounds__(256) void norm_h_kernel(
    u16* __restrict__ H, const float* __restrict__ sumsq, int step)
{
  float s = invs(sumsq[step]);
  size_t base = (size_t)step*G_STEP*256 + ((size_t)blockIdx.x*256 + threadIdx.x)*8;
  uint4 v = *reinterpret_cast<const uint4*>(H + base);
  uint4 o;
  #define MUL2(p) ( (u32)f2bfu(bfu2f((u16)((p)&0xffff))*s) | ((u32)f2bfu(bfu2f((u16)((p)>>16))*s) << 16) )
  o.x = MUL2(v.x); o.y = MUL2(v.y); o.z = MUL2(v.z); o.w = MUL2(v.w);
  #undef MUL2
  *reinterpret_cast<uint4*>(H + base) = o;
}

// ---------------------------------------------------------------- output: convert; scale step-15 rows only
__global__ __launch_bounds__(256) void out_kernel(
    const u16* __restrict__ H, const float* __restrict__ sumsq, float* __restrict__ out)
{
  size_t base = ((size_t)blockIdx.x*256 + threadIdx.x)*8;
  int n = (int)(base >> 8);
  float s = ((n >> 13) == 15) ? invs(sumsq[15]) : 1.0f;
  const uint4 v = *reinterpret_cast<const uint4*>(H + base);
  float4 o0, o1;
  o0.x = bfu2f((u16)(v.x & 0xffff))*s; o0.y = bfu2f((u16)(v.x >> 16))*s;
  o0.z = bfu2f((u16)(v.y & 0xffff))*s; o0.w = bfu2f((u16)(v.y >> 16))*s;
  o1.x = bfu2f((u16)(v.z & 0xffff))*s; o1.y = bfu2f((u16)(v.z >> 16))*s;
  o1.z = bfu2f((u16)(v.w & 0xffff))*s; o1.w = bfu2f((u16)(v.w >> 16))*s;
  *reinterpret_cast<float4*>(out + base)     = o0;
  *reinterpret_cast<float4*>(out + base + 4) = o1;
}

// ---------------------------------------------------------------- host
extern "C" void kernel_launch(void* const* d_in, const int* in_sizes, int n_in,
                              void* d_out, int out_size, void* d_ws, size_t ws_size,
                              hipStream_t stream)
{
  const int*   tokens     = (const int*)d_in[0];
  const int*   lidx       = (const int*)d_in[1];
  const int*   ridx       = (const int*)d_in[2];
  const float* leaf_table = (const float*)d_in[6];
  const float* num_W1     = (const float*)d_in[7];
  const float* num_b1     = (const float*)d_in[8];
  const float* num_W2     = (const float*)d_in[9];
  const float* num_b2     = (const float*)d_in[10];
  const float* una_W      = (const float*)d_in[11];
  const float* una_b      = (const float*)d_in[12];
  const float* bin_W      = (const float*)d_in[13];
  const float* bin_b      = (const float*)d_in[14];

  // ws layout: H | wbu | wbb | wbn | h1 | sumsq
  char* ws = (char*)d_ws;
  size_t off = 0;
  u16* H   = (u16*)(ws + off); off += (size_t)N_TOTAL*256*2;
  u16* wbu = (u16*)(ws + off); off += (size_t)2048*256*2;
  u16* wbb = (u16*)(ws + off); off += (size_t)5120*256*2;
  u16* wbn = (u16*)(ws + off); off += (size_t)256*256*2;
  u16* h1  = (u16*)(ws + off); off += (size_t)G_STEP*256*2;
  float* sumsq = (float*)(ws + off); off += 32*4;

  u16* C = (u16*)d_out;  // dead before out_kernel overwrites

  setup_kernel<<<4001, 256, 0, stream>>>(tokens, leaf_table, num_W1, num_b1,
                                         una_W, bin_W, num_W2,
                                         wbu, wbb, wbn, h1, H, C, sumsq);
  gemm_fused<0><<<dim3(64, 2), 256, 0, stream>>>(
      h1, nullptr, nullptr, wbn, num_b2, nullptr, sumsq, H, C, G_STEP, 1);

  const int sched[16] = {-1,-2,0,2,1,3,0,2,1,3,0,2,1,3,0,2};
  for (int d = 2; d < 16; d++){
    int op = sched[d];
    int sbase = d*G_STEP;
    if (op == 0 || op == 1){
      gemm_fused<1><<<dim3(64, 8), 256, 0, stream>>>(
          H, lidx, nullptr, wbu + (size_t)op*1024*256,
          una_b + (size_t)op*4*256, C, sumsq, H, C, sbase, d);
    } else {
      int o2 = op - 2;
      gemm_fused<2><<<dim3(64, 8), 256, 0, stream>>>(
          H, lidx, ridx, wbb + (size_t)o2*2*1280*256,
          bin_b + (size_t)o2*5*256, C, sumsq, H, C, sbase, d);
    }
    if (d < 15) norm_h_kernel<<<1024, 256, 0, stream>>>(H, sumsq, d);
  }
  out_kernel<<<(N_TOTAL*256)/(256*8), 256, 0, stream>>>(H, sumsq, (float*)d_out);
}

// Round 4
// 381.700 us; speedup vs baseline: 3.1837x; 1.0476x over previous
//
#include <hip/hip_runtime.h>
#include <hip/hip_bf16.h>
#include <cstdint>

typedef unsigned short u16;
typedef unsigned int u32;
typedef __attribute__((ext_vector_type(4))) float floatx4;
typedef __attribute__((ext_vector_type(8))) short shortx8;

#define G_STEP 8192
#define N_TOTAL 131072
#define RHALF (1280*256)

__device__ __forceinline__ float bfu2f(u16 x){ return __uint_as_float(((unsigned)x)<<16); }
__device__ __forceinline__ u16 f2bfu(float x){ __hip_bfloat16 b = __float2bfloat16(x); return *reinterpret_cast<u16*>(&b); }
__device__ __forceinline__ float sigm(float x){ return 1.0f/(1.0f+__expf(-x)); }
__device__ __forceinline__ float tanh_(float x){
  float cx = fminf(fmaxf(x,-15.f),15.f);
  float e = __expf(2.f*cx);
  return (e-1.f)/(e+1.f);
}
__device__ __forceinline__ float invs(float x){ return 1.0f/sqrtf(x); }

__device__ __forceinline__ void gl16(const void* g, void* l){
  __builtin_amdgcn_global_load_lds((const __attribute__((address_space(1))) u32*)g,
                                   (__attribute__((address_space(3))) u32*)l, 16, 0, 0);
}

__device__ __forceinline__ void cvt8(const float* __restrict__ src, u16* __restrict__ dst){
  float4 a = *reinterpret_cast<const float4*>(src);
  float4 b = *reinterpret_cast<const float4*>(src+4);
  ushort4 o0; o0.x=f2bfu(a.x); o0.y=f2bfu(a.y); o0.z=f2bfu(a.z); o0.w=f2bfu(a.w);
  ushort4 o1; o1.x=f2bfu(b.x); o1.y=f2bfu(b.y); o1.z=f2bfu(b.z); o1.w=f2bfu(b.w);
  *reinterpret_cast<ushort4*>(dst)   = o0;
  *reinterpret_cast<ushort4*>(dst+4) = o1;
}

// ---------------------------------------------------------------- setup (fused prep + leaf + num_pre + sumsq init)
// Weight layouts (bf16):
//  wbu[op][eblk(16)][gate(4)][el(16)][d]   rows = op*1024 + eblk*64 + gate*16 + el
//  wbb[ob][lr(2)][eblk(16)][gate(5)][el(16)][d] rows = ((ob*2+lr)*1280) + eblk*80 + gate*16 + el
//  wbn[e][d] plain
__global__ __launch_bounds__(256) void setup_kernel(
    const int* __restrict__ tokens, const float* __restrict__ leaf_table,
    const float* __restrict__ W1, const float* __restrict__ b1,
    const float* __restrict__ una_W, const float* __restrict__ bin_W,
    const float* __restrict__ num_W2,
    u16* __restrict__ wbu, u16* __restrict__ wbb, u16* __restrict__ wbn,
    u16* __restrict__ h1, u16* __restrict__ H, u16* __restrict__ C,
    float* __restrict__ sumsq)
{
  const int b = blockIdx.x, tid = threadIdx.x;
  if (b < 256){                                  // wbu: 2048 rows
    int row = b*8 + (tid>>5), d0 = (tid&31)*8;
    int op = row>>10, w = row&1023;
    int gate = (w>>4)&3, e = ((w>>6)<<4) | (w&15);
    cvt8(una_W + (size_t)((op*4+gate)*256 + e)*256 + d0, wbu + (size_t)row*256 + d0);
  } else if (b < 896){                           // wbb: 5120 rows
    int row = (b-256)*8 + (tid>>5), d0 = (tid&31)*8;
    int ob = row / 2560, rem = row - ob*2560;
    int lr = rem / 1280, rw = rem - lr*1280;
    int eblk = rw / 80, rem2 = rw - eblk*80;
    int gate = rem2 >> 4, el = rem2 & 15;
    int e = eblk*16 + el;
    cvt8(bin_W + (size_t)((ob*10 + 2*gate + lr)*256 + e)*256 + d0, wbb + (size_t)row*256 + d0);
  } else if (b < 928){                           // wbn: 256 rows plain
    int row = (b-896)*8 + (tid>>5), d0 = (tid&31)*8;
    cvt8(num_W2 + (size_t)row*256 + d0, wbn + (size_t)row*256 + d0);
  } else if (b < 2976){                          // leaf: 8192 nodes, 4/block
    int wave = tid >> 6, lane = tid & 63;
    int node = (b-928)*4 + wave;
    int t = tokens[node];
    const float4 e4 = *reinterpret_cast<const float4*>(leaf_table + (size_t)t*256 + lane*4);
    float ss = e4.x*e4.x + e4.y*e4.y + e4.z*e4.z + e4.w*e4.w;
    #pragma unroll
    for (int o = 32; o; o >>= 1) ss += __shfl_down(ss, o);
    ss = __shfl(ss, 0);
    float scale = fminf(1.0f, 1.0f/(sqrtf(ss) + 1e-7f));
    ushort4 hv;
    hv.x = f2bfu(e4.x*scale); hv.y = f2bfu(e4.y*scale);
    hv.z = f2bfu(e4.z*scale); hv.w = f2bfu(e4.w*scale);
    ushort4 zv; zv.x = zv.y = zv.z = zv.w = 0;
    *reinterpret_cast<ushort4*>(H + (size_t)node*256 + lane*4) = hv;
    *reinterpret_cast<ushort4*>(C + (size_t)node*256 + lane*4) = zv;
  } else if (b < 4000){                          // num_pre: 2M elems, 8/thread
    int flat = (b-2976)*2048 + tid*8;
    int n = flat >> 8, d0 = flat & 255;
    float x = (float)tokens[G_STEP + n];
    float4 w0 = *reinterpret_cast<const float4*>(W1 + d0);
    float4 w1 = *reinterpret_cast<const float4*>(W1 + d0 + 4);
    float4 c0 = *reinterpret_cast<const float4*>(b1 + d0);
    float4 c1 = *reinterpret_cast<const float4*>(b1 + d0 + 4);
    ushort4 o0, o1;
    o0.x = f2bfu(sigm(x*w0.x + c0.x)); o0.y = f2bfu(sigm(x*w0.y + c0.y));
    o0.z = f2bfu(sigm(x*w0.z + c0.z)); o0.w = f2bfu(sigm(x*w0.w + c0.w));
    o1.x = f2bfu(sigm(x*w1.x + c1.x)); o1.y = f2bfu(sigm(x*w1.y + c1.y));
    o1.z = f2bfu(sigm(x*w1.z + c1.z)); o1.w = f2bfu(sigm(x*w1.w + c1.w));
    *reinterpret_cast<ushort4*>(h1 + flat)     = o0;
    *reinterpret_cast<ushort4*>(h1 + flat + 4) = o1;
  } else {                                       // sumsq init
    if (tid < 32) sumsq[tid] = ((tid & 15) < 2) ? 1.0f : 0.0f;
  }
}

// ---------------------------------------------------------------- fused GEMM + LSTM cell, deferred H-norm
// H holds UNNORMALIZED h; per-child scale invs(sumsq[step]) applied to accumulators
// in the epilogue (GEMM linear in A). Binary uses split accL/accR over K-halves.
// MODE 0: numeric  A=h1, K=256, 256 cols,  epi: H=sigm(g+b2), C=0
// MODE 1: unary    A=H[lidx], K=256, 1024 cols (gate-tiled), epi: 4-gate cell
// MODE 2: binary   A=[H[l]|H[r]] concat-K 512, 1280 cols (gate-tiled), epi: 5-gate cell
template<int MODE>
__global__ __launch_bounds__(256, 2) void gemm_fused(
    const u16* __restrict__ Asrc, const int* __restrict__ lidx,
    const int* __restrict__ ridx, const u16* __restrict__ Wb,
    const float* __restrict__ bias, const u16* __restrict__ Cin,
    float* __restrict__ sumsq, u16* __restrict__ H, u16* __restrict__ C,
    int sbase, int step)
{
  constexpr int NG  = (MODE==0) ? 1 : (MODE==1 ? 4 : 5);
  constexpr int NBR = (MODE==2) ? 160 : 128;
  constexpr int NT  = (MODE==2) ? 8 : 4;
  constexpr int BR  = NBR/32;
  constexpr int WN  = (MODE==2) ? 80 : 64;
  constexpr int NFR = WN/16;

  __shared__ u16 SA[2][128][64];
  __shared__ u16 SB[2][NBR][64];
  __shared__ float scH[16];
  __shared__ float scC[16];
  __shared__ float red[8];

  const int tid  = threadIdx.x;
  const int lane = tid & 63, wave = tid >> 6;
  const int mbase = blockIdx.x*128;
  const int nbase = blockIdx.y*NBR;
  const int l15 = lane & 15, kg = lane >> 4;
  const int rhi = lane >> 3;
  const int lc  = (lane & 7) ^ rhi;

  if (MODE != 0){
    if (tid < 16)           scH[tid]    = invs(sumsq[tid]);
    else if (tid < 32)      scC[tid-16] = invs(sumsq[tid]);
  }

  const u16* aL[4]; const u16* aR[4]; const u16* bP[BR];
  #pragma unroll
  for (int rr = 0; rr < 4; rr++){
    int r = rr*32 + wave*8 + rhi;
    int gr;
    if constexpr (MODE==0) gr = mbase + r;
    else                   gr = lidx[sbase + mbase + r];
    aL[rr] = Asrc + (size_t)gr*256 + lc*8;
    if constexpr (MODE==2)
      aR[rr] = Asrc + (size_t)ridx[sbase + mbase + r]*256 + lc*8;
  }
  #pragma unroll
  for (int rb = 0; rb < BR; rb++){
    int r = rb*32 + wave*8 + rhi;
    bP[rb] = Wb + (size_t)(nbase + r)*256 + lc*8;
  }

  floatx4 accL[4][NFR];
  #pragma unroll
  for (int i = 0; i < 4; i++)
    #pragma unroll
    for (int j = 0; j < NFR; j++) accL[i][j] = (floatx4)(0.0f);
  floatx4 accR[(MODE==2)?4:1][(MODE==2)?NFR:1];
  if constexpr (MODE==2){
    #pragma unroll
    for (int i = 0; i < 4; i++)
      #pragma unroll
      for (int j = 0; j < NFR; j++) accR[i][j] = (floatx4)(0.0f);
  }

  const int wm = (wave >> 1)*64, wn = (wave & 1)*WN;

  auto stage = [&](int t, int buf){
    const int kk = t*64;
    #pragma unroll
    for (int rr = 0; rr < 4; rr++){
      const u16* ga;
      if constexpr (MODE==2){ ga = (kk >= 256) ? aR[rr] + (kk-256) : aL[rr] + kk; }
      else                  { ga = aL[rr] + kk; }
      gl16(ga, &SA[buf][rr*32 + wave*8][0]);
    }
    #pragma unroll
    for (int rb = 0; rb < BR; rb++){
      const u16* gb;
      if constexpr (MODE==2){ gb = (kk >= 256) ? bP[rb] + RHALF + (kk-256) : bP[rb] + kk; }
      else                  { gb = bP[rb] + kk; }
      gl16(gb, &SB[buf][rb*32 + wave*8][0]);
    }
  };

  stage(0, 0);
  __syncthreads();

  #pragma unroll
  for (int t = 0; t < NT; t++){
    if (t+1 < NT) stage(t+1, (t+1)&1);
    const int buf = t & 1;
    #pragma unroll
    for (int j = 0; j < 2; j++){
      shortx8 af[4], bfr[NFR];
      const int pc = ((j*4 + kg) ^ (l15 & 7)) * 8;
      #pragma unroll
      for (int i = 0; i < 4; i++)
        af[i] = *reinterpret_cast<const shortx8*>(&SA[buf][wm + i*16 + l15][pc]);
      #pragma unroll
      for (int n = 0; n < NFR; n++)
        bfr[n] = *reinterpret_cast<const shortx8*>(&SB[buf][wn + n*16 + l15][pc]);
      if (MODE==2 && t >= 4){
        #pragma unroll
        for (int mi = 0; mi < 4; mi++)
          #pragma unroll
          for (int ni = 0; ni < NFR; ni++)
            accR[mi][ni] = __builtin_amdgcn_mfma_f32_16x16x32_bf16(af[mi], bfr[ni], accR[mi][ni], 0, 0, 0);
      } else {
        #pragma unroll
        for (int mi = 0; mi < 4; mi++)
          #pragma unroll
          for (int ni = 0; ni < NFR; ni++)
            accL[mi][ni] = __builtin_amdgcn_mfma_f32_16x16x32_bf16(af[mi], bfr[ni], accL[mi][ni], 0, 0, 0);
      }
    }
    __syncthreads();
  }

  // ---------------- fused epilogue ----------------
  if constexpr (MODE == 0){
    float bb[4];
    #pragma unroll
    for (int ni = 0; ni < 4; ni++) bb[ni] = bias[nbase + wn + ni*16 + l15];
    #pragma unroll
    for (int mi = 0; mi < 4; mi++){
      #pragma unroll
      for (int r = 0; r < 4; r++){
        int node = sbase + mbase + wm + mi*16 + kg*4 + r;
        u16* hp = H + (size_t)node*256 + nbase + wn + l15;
        u16* cp = C + (size_t)node*256 + nbase + wn + l15;
        #pragma unroll
        for (int ni = 0; ni < 4; ni++){
          hp[ni*16] = f2bfu(sigm(accL[mi][ni][r] + bb[ni]));
          cp[ni*16] = 0;
        }
      }
    }
  } else {
    const int eb = blockIdx.y*2 + (wave & 1);
    const int e  = eb*16 + l15;
    float bb[NG];
    #pragma unroll
    for (int g = 0; g < NG; g++) bb[g] = bias[g*256 + e];
    float hss = 0.f, css = 0.f;
    #pragma unroll
    for (int mi = 0; mi < 4; mi++){
      #pragma unroll
      for (int r = 0; r < 4; r++){
        int orow = mbase + wm + mi*16 + kg*4 + r;
        int node = sbase + orow;
        int chl = lidx[node];
        float sl = scH[chl >> 13];
        float cl = bfu2f(Cin[(size_t)chl*256 + e]) * scC[chl >> 13];
        float c2, h2;
        if constexpr (MODE == 1){
          float i_ = sigm(accL[mi][0][r]*sl + bb[0]);
          float f_ = sigm(accL[mi][1][r]*sl + bb[1]);
          float o_ = sigm(accL[mi][2][r]*sl + bb[2]);
          float u_ = tanh_(accL[mi][3][r]*sl + bb[3]);
          c2 = i_*u_ + f_*cl;
          h2 = o_*tanh_(c2);
        } else {
          int chr = ridx[node];
          float sr = scH[chr >> 13];
          float cr = bfu2f(Cin[(size_t)chr*256 + e]) * scC[chr >> 13];
          float g0 = accL[mi][0][r]*sl + accR[mi][0][r]*sr + bb[0];
          float g1 = accL[mi][1][r]*sl + accR[mi][1][r]*sr + bb[1];
          float g2 = accL[mi][2][r]*sl + accR[mi][2][r]*sr + bb[2];
          float g3 = accL[mi][3][r]*sl + accR[mi][3][r]*sr + bb[3];
          float g4 = accL[mi][4][r]*sl + accR[mi][4][r]*sr + bb[4];
          float i_ = sigm(g0);
          float fl = sigm(g1);
          float fr = sigm(g2);
          float o_ = sigm(g3);
          float u_ = tanh_(g4);
          c2 = i_*u_ + fl*cl + fr*cr;
          h2 = o_*tanh_(c2);
        }
        H[(size_t)node*256 + e] = f2bfu(h2);
        C[(size_t)node*256 + e] = f2bfu(c2);
        hss += h2*h2;
        css += c2*c2;
      }
    }
    #pragma unroll
    for (int o = 32; o; o >>= 1){ hss += __shfl_down(hss, o); css += __shfl_down(css, o); }
    if (lane == 0){ red[wave] = hss; red[4+wave] = css; }
    __syncthreads();
    if (tid == 0)  atomicAdd(&sumsq[step],      red[0]+red[1]+red[2]+red[3]);
    if (tid == 64) atomicAdd(&sumsq[16 + step], red[4]+red[5]+red[6]+red[7]);
  }
}

// ---------------------------------------------------------------- output: bf16->f32 with per-step H scale
__global__ __launch_bounds__(256) void out_kernel(
    const u16* __restrict__ H, const float* __restrict__ sumsq, float* __restrict__ out)
{
  size_t base = ((size_t)blockIdx.x*256 + threadIdx.x)*8;
  int n = (int)(base >> 8);
  float s = invs(sumsq[n >> 13]);
  const uint4 v = *reinterpret_cast<const uint4*>(H + base);
  float4 o0, o1;
  o0.x = bfu2f((u16)(v.x & 0xffff))*s; o0.y = bfu2f((u16)(v.x >> 16))*s;
  o0.z = bfu2f((u16)(v.y & 0xffff))*s; o0.w = bfu2f((u16)(v.y >> 16))*s;
  o1.x = bfu2f((u16)(v.z & 0xffff))*s; o1.y = bfu2f((u16)(v.z >> 16))*s;
  o1.z = bfu2f((u16)(v.w & 0xffff))*s; o1.w = bfu2f((u16)(v.w >> 16))*s;
  *reinterpret_cast<float4*>(out + base)     = o0;
  *reinterpret_cast<float4*>(out + base + 4) = o1;
}

// ---------------------------------------------------------------- host
extern "C" void kernel_launch(void* const* d_in, const int* in_sizes, int n_in,
                              void* d_out, int out_size, void* d_ws, size_t ws_size,
                              hipStream_t stream)
{
  const int*   tokens     = (const int*)d_in[0];
  const int*   lidx       = (const int*)d_in[1];
  const int*   ridx       = (const int*)d_in[2];
  const float* leaf_table = (const float*)d_in[6];
  const float* num_W1     = (const float*)d_in[7];
  const float* num_b1     = (const float*)d_in[8];
  const float* num_W2     = (const float*)d_in[9];
  const float* num_b2     = (const float*)d_in[10];
  const float* una_W      = (const float*)d_in[11];
  const float* una_b      = (const float*)d_in[12];
  const float* bin_W      = (const float*)d_in[13];
  const float* bin_b      = (const float*)d_in[14];

  // ws layout: H | wbu | wbb | wbn | h1 | sumsq
  char* ws = (char*)d_ws;
  size_t off = 0;
  u16* H   = (u16*)(ws + off); off += (size_t)N_TOTAL*256*2;
  u16* wbu = (u16*)(ws + off); off += (size_t)2048*256*2;
  u16* wbb = (u16*)(ws + off); off += (size_t)5120*256*2;
  u16* wbn = (u16*)(ws + off); off += (size_t)256*256*2;
  u16* h1  = (u16*)(ws + off); off += (size_t)G_STEP*256*2;
  float* sumsq = (float*)(ws + off); off += 32*4;

  u16* C = (u16*)d_out;  // dead before out_kernel overwrites

  setup_kernel<<<4001, 256, 0, stream>>>(tokens, leaf_table, num_W1, num_b1,
                                         una_W, bin_W, num_W2,
                                         wbu, wbb, wbn, h1, H, C, sumsq);
  gemm_fused<0><<<dim3(64, 2), 256, 0, stream>>>(
      h1, nullptr, nullptr, wbn, num_b2, nullptr, sumsq, H, C, G_STEP, 1);

  const int sched[16] = {-1,-2,0,2,1,3,0,2,1,3,0,2,1,3,0,2};
  for (int d = 2; d < 16; d++){
    int op = sched[d];
    int sbase = d*G_STEP;
    if (op == 0 || op == 1){
      gemm_fused<1><<<dim3(64, 8), 256, 0, stream>>>(
          H, lidx, nullptr, wbu + (size_t)op*1024*256,
          una_b + (size_t)op*4*256, C, sumsq, H, C, sbase, d);
    } else {
      int o2 = op - 2;
      gemm_fused<2><<<dim3(64, 8), 256, 0, stream>>>(
          H, lidx, ridx, wbb + (size_t)o2*2*1280*256,
          bin_b + (size_t)o2*5*256, C, sumsq, H, C, sbase, d);
    }
  }
  out_kernel<<<(N_TOTAL*256)/(256*8), 256, 0, stream>>>(H, sumsq, (float*)d_out);
}

// Round 5
// 369.550 us; speedup vs baseline: 3.2884x; 1.0329x over previous
//
#include <hip/hip_runtime.h>
#include <hip/hip_bf16.h>
#include <cstdint>

typedef unsigned short u16;
typedef unsigned int u32;
typedef __attribute__((ext_vector_type(4))) float floatx4;
typedef __attribute__((ext_vector_type(8))) short shortx8;

#define G_STEP 8192
#define N_TOTAL 131072
#define RHALF (1280*256)

__device__ __forceinline__ float bfu2f(u16 x){ return __uint_as_float(((unsigned)x)<<16); }
__device__ __forceinline__ u16 f2bfu(float x){ __hip_bfloat16 b = __float2bfloat16(x); return *reinterpret_cast<u16*>(&b); }
__device__ __forceinline__ float sigm(float x){ return 1.0f/(1.0f+__expf(-x)); }
__device__ __forceinline__ float tanh_(float x){
  float cx = fminf(fmaxf(x,-15.f),15.f);
  float e = __expf(2.f*cx);
  return (e-1.f)/(e+1.f);
}
__device__ __forceinline__ float invs(float x){ return 1.0f/sqrtf(x); }

__device__ __forceinline__ void gl16(const void* g, void* l){
  __builtin_amdgcn_global_load_lds((const __attribute__((address_space(1))) u32*)g,
                                   (__attribute__((address_space(3))) u32*)l, 16, 0, 0);
}

// counted waits (memory clobber so VMEM/DS ops can't cross)
template<int V> __device__ __forceinline__ void wait_vm();
template<> __device__ __forceinline__ void wait_vm<0>(){ asm volatile("s_waitcnt vmcnt(0)" ::: "memory"); }
template<> __device__ __forceinline__ void wait_vm<8>(){ asm volatile("s_waitcnt vmcnt(8)" ::: "memory"); }
template<> __device__ __forceinline__ void wait_vm<9>(){ asm volatile("s_waitcnt vmcnt(9)" ::: "memory"); }
__device__ __forceinline__ void wait_lgkm0(){ asm volatile("s_waitcnt lgkmcnt(0)" ::: "memory"); }

__device__ __forceinline__ void cvt8(const float* __restrict__ src, u16* __restrict__ dst){
  float4 a = *reinterpret_cast<const float4*>(src);
  float4 b = *reinterpret_cast<const float4*>(src+4);
  ushort4 o0; o0.x=f2bfu(a.x); o0.y=f2bfu(a.y); o0.z=f2bfu(a.z); o0.w=f2bfu(a.w);
  ushort4 o1; o1.x=f2bfu(b.x); o1.y=f2bfu(b.y); o1.z=f2bfu(b.z); o1.w=f2bfu(b.w);
  *reinterpret_cast<ushort4*>(dst)   = o0;
  *reinterpret_cast<ushort4*>(dst+4) = o1;
}

// ---------------------------------------------------------------- setup (fused prep + leaf + num_pre + sumsq init)
__global__ __launch_bounds__(256) void setup_kernel(
    const int* __restrict__ tokens, const float* __restrict__ leaf_table,
    const float* __restrict__ W1, const float* __restrict__ b1,
    const float* __restrict__ una_W, const float* __restrict__ bin_W,
    const float* __restrict__ num_W2,
    u16* __restrict__ wbu, u16* __restrict__ wbb, u16* __restrict__ wbn,
    u16* __restrict__ h1, u16* __restrict__ H, u16* __restrict__ C,
    float* __restrict__ sumsq)
{
  const int b = blockIdx.x, tid = threadIdx.x;
  if (b < 256){                                  // wbu: 2048 rows
    int row = b*8 + (tid>>5), d0 = (tid&31)*8;
    int op = row>>10, w = row&1023;
    int gate = (w>>4)&3, e = ((w>>6)<<4) | (w&15);
    cvt8(una_W + (size_t)((op*4+gate)*256 + e)*256 + d0, wbu + (size_t)row*256 + d0);
  } else if (b < 896){                           // wbb: 5120 rows
    int row = (b-256)*8 + (tid>>5), d0 = (tid&31)*8;
    int ob = row / 2560, rem = row - ob*2560;
    int lr = rem / 1280, rw = rem - lr*1280;
    int eblk = rw / 80, rem2 = rw - eblk*80;
    int gate = rem2 >> 4, el = rem2 & 15;
    int e = eblk*16 + el;
    cvt8(bin_W + (size_t)((ob*10 + 2*gate + lr)*256 + e)*256 + d0, wbb + (size_t)row*256 + d0);
  } else if (b < 928){                           // wbn: 256 rows plain
    int row = (b-896)*8 + (tid>>5), d0 = (tid&31)*8;
    cvt8(num_W2 + (size_t)row*256 + d0, wbn + (size_t)row*256 + d0);
  } else if (b < 2976){                          // leaf: 8192 nodes, 4/block
    int wave = tid >> 6, lane = tid & 63;
    int node = (b-928)*4 + wave;
    int t = tokens[node];
    const float4 e4 = *reinterpret_cast<const float4*>(leaf_table + (size_t)t*256 + lane*4);
    float ss = e4.x*e4.x + e4.y*e4.y + e4.z*e4.z + e4.w*e4.w;
    #pragma unroll
    for (int o = 32; o; o >>= 1) ss += __shfl_down(ss, o);
    ss = __shfl(ss, 0);
    float scale = fminf(1.0f, 1.0f/(sqrtf(ss) + 1e-7f));
    ushort4 hv;
    hv.x = f2bfu(e4.x*scale); hv.y = f2bfu(e4.y*scale);
    hv.z = f2bfu(e4.z*scale); hv.w = f2bfu(e4.w*scale);
    ushort4 zv; zv.x = zv.y = zv.z = zv.w = 0;
    *reinterpret_cast<ushort4*>(H + (size_t)node*256 + lane*4) = hv;
    *reinterpret_cast<ushort4*>(C + (size_t)node*256 + lane*4) = zv;
  } else if (b < 4000){                          // num_pre: 2M elems, 8/thread
    int flat = (b-2976)*2048 + tid*8;
    int n = flat >> 8, d0 = flat & 255;
    float x = (float)tokens[G_STEP + n];
    float4 w0 = *reinterpret_cast<const float4*>(W1 + d0);
    float4 w1 = *reinterpret_cast<const float4*>(W1 + d0 + 4);
    float4 c0 = *reinterpret_cast<const float4*>(b1 + d0);
    float4 c1 = *reinterpret_cast<const float4*>(b1 + d0 + 4);
    ushort4 o0, o1;
    o0.x = f2bfu(sigm(x*w0.x + c0.x)); o0.y = f2bfu(sigm(x*w0.y + c0.y));
    o0.z = f2bfu(sigm(x*w0.z + c0.z)); o0.w = f2bfu(sigm(x*w0.w + c0.w));
    o1.x = f2bfu(sigm(x*w1.x + c1.x)); o1.y = f2bfu(sigm(x*w1.y + c1.y));
    o1.z = f2bfu(sigm(x*w1.z + c1.z)); o1.w = f2bfu(sigm(x*w1.w + c1.w));
    *reinterpret_cast<ushort4*>(h1 + flat)     = o0;
    *reinterpret_cast<ushort4*>(h1 + flat + 4) = o1;
  } else {                                       // sumsq init
    if (tid < 32) sumsq[tid] = ((tid & 15) < 2) ? 1.0f : 0.0f;
  }
}

// ---------------------------------------------------------------- fused GEMM + LSTM cell, deferred H-norm
// Counted-vmcnt 2-deep pipeline (T3/T4): prefetch never drained at barriers.
// MODE 0: numeric  A=h1, K=256, 256 cols,  epi: H=sigm(g+b2), C=0
// MODE 1: unary    A=H[lidx], K=256, 1024 cols (gate-tiled), epi: 4-gate cell
// MODE 2: binary   A=[H[l]|H[r]] concat-K 512, 1280 cols (gate-tiled), epi: 5-gate cell
template<int MODE>
__global__ __launch_bounds__(256, 2) void gemm_fused(
    const u16* __restrict__ Asrc, const int* __restrict__ lidx,
    const int* __restrict__ ridx, const u16* __restrict__ Wb,
    const float* __restrict__ bias, const u16* __restrict__ Cin,
    float* __restrict__ sumsq, u16* __restrict__ H, u16* __restrict__ C,
    int sbase, int step)
{
  constexpr int NG  = (MODE==0) ? 1 : (MODE==1 ? 4 : 5);
  constexpr int NBR = (MODE==2) ? 160 : 128;
  constexpr int NT  = (MODE==2) ? 8 : 4;
  constexpr int BR  = NBR/32;
  constexpr int WN  = (MODE==2) ? 80 : 64;
  constexpr int NFR = WN/16;
  constexpr int LPS = 4 + BR;                   // global_load_lds per wave per stage

  __shared__ u16 SA[2][128][64];
  __shared__ u16 SB[2][NBR][64];
  __shared__ float scH[16];
  __shared__ float scC[16];
  __shared__ float red[8];

  const int tid  = threadIdx.x;
  const int lane = tid & 63, wave = tid >> 6;
  const int mbase = blockIdx.x*128;
  const int nbase = blockIdx.y*NBR;
  const int l15 = lane & 15, kg = lane >> 4;
  const int rhi = lane >> 3;
  const int lc  = (lane & 7) ^ rhi;

  if (MODE != 0){
    if (tid < 16)           scH[tid]    = invs(sumsq[tid]);
    else if (tid < 32)      scC[tid-16] = invs(sumsq[tid]);
  }

  const u16* aL[4]; const u16* aR[4]; const u16* bP[BR];
  #pragma unroll
  for (int rr = 0; rr < 4; rr++){
    int r = rr*32 + wave*8 + rhi;
    int gr;
    if constexpr (MODE==0) gr = mbase + r;
    else                   gr = lidx[sbase + mbase + r];
    aL[rr] = Asrc + (size_t)gr*256 + lc*8;
    if constexpr (MODE==2)
      aR[rr] = Asrc + (size_t)ridx[sbase + mbase + r]*256 + lc*8;
  }
  #pragma unroll
  for (int rb = 0; rb < BR; rb++){
    int r = rb*32 + wave*8 + rhi;
    bP[rb] = Wb + (size_t)(nbase + r)*256 + lc*8;
  }

  floatx4 accL[4][NFR];
  #pragma unroll
  for (int i = 0; i < 4; i++)
    #pragma unroll
    for (int j = 0; j < NFR; j++) accL[i][j] = (floatx4)(0.0f);
  floatx4 accR[(MODE==2)?4:1][(MODE==2)?NFR:1];
  if constexpr (MODE==2){
    #pragma unroll
    for (int i = 0; i < 4; i++)
      #pragma unroll
      for (int j = 0; j < NFR; j++) accR[i][j] = (floatx4)(0.0f);
  }

  const int wm = (wave >> 1)*64, wn = (wave & 1)*WN;

  auto stage = [&](int t, int buf){
    const int kk = t*64;
    #pragma unroll
    for (int rr = 0; rr < 4; rr++){
      const u16* ga;
      if constexpr (MODE==2){ ga = (kk >= 256) ? aR[rr] + (kk-256) : aL[rr] + kk; }
      else                  { ga = aL[rr] + kk; }
      gl16(ga, &SA[buf][rr*32 + wave*8][0]);
    }
    #pragma unroll
    for (int rb = 0; rb < BR; rb++){
      const u16* gb;
      if constexpr (MODE==2){ gb = (kk >= 256) ? bP[rb] + RHALF + (kk-256) : bP[rb] + kk; }
      else                  { gb = bP[rb] + kk; }
      gl16(gb, &SB[buf][rb*32 + wave*8][0]);
    }
  };

  // prologue: 2-deep prefetch; wait only for stage(0); drain LDS writes (scH/scC)
  stage(0, 0);
  stage(1, 1);
  if constexpr (LPS == 8) asm volatile("s_waitcnt vmcnt(8) lgkmcnt(0)" ::: "memory");
  else                    asm volatile("s_waitcnt vmcnt(9) lgkmcnt(0)" ::: "memory");
  __builtin_amdgcn_s_barrier();

  #pragma unroll
  for (int t = 0; t < NT; t++){
    const int buf = t & 1;
    // ---- j = 0 ----
    {
      shortx8 af[4], bfr[NFR];
      const int pc = (kg ^ (l15 & 7)) * 8;
      #pragma unroll
      for (int i = 0; i < 4; i++)
        af[i] = *reinterpret_cast<const shortx8*>(&SA[buf][wm + i*16 + l15][pc]);
      #pragma unroll
      for (int n = 0; n < NFR; n++)
        bfr[n] = *reinterpret_cast<const shortx8*>(&SB[buf][wn + n*16 + l15][pc]);
      if (MODE==2 && t >= 4){
        #pragma unroll
        for (int mi = 0; mi < 4; mi++)
          #pragma unroll
          for (int ni = 0; ni < NFR; ni++)
            accR[mi][ni] = __builtin_amdgcn_mfma_f32_16x16x32_bf16(af[mi], bfr[ni], accR[mi][ni], 0, 0, 0);
      } else {
        #pragma unroll
        for (int mi = 0; mi < 4; mi++)
          #pragma unroll
          for (int ni = 0; ni < NFR; ni++)
            accL[mi][ni] = __builtin_amdgcn_mfma_f32_16x16x32_bf16(af[mi], bfr[ni], accL[mi][ni], 0, 0, 0);
      }
    }
    // ---- j = 1 : read frags, free the buffer, restage it, then MFMA ----
    {
      shortx8 af[4], bfr[NFR];
      const int pc = ((4 + kg) ^ (l15 & 7)) * 8;
      #pragma unroll
      for (int i = 0; i < 4; i++)
        af[i] = *reinterpret_cast<const shortx8*>(&SA[buf][wm + i*16 + l15][pc]);
      #pragma unroll
      for (int n = 0; n < NFR; n++)
        bfr[n] = *reinterpret_cast<const shortx8*>(&SB[buf][wn + n*16 + l15][pc]);
      wait_lgkm0();                       // my reads of buf landed in regs
      __builtin_amdgcn_s_barrier();       // all waves done reading buf
      if (t + 2 < NT) stage(t+2, buf);    // overwrite buf; latency hidden by MFMAs below
      if (MODE==2 && t >= 4){
        #pragma unroll
        for (int mi = 0; mi < 4; mi++)
          #pragma unroll
          for (int ni = 0; ni < NFR; ni++)
            accR[mi][ni] = __builtin_amdgcn_mfma_f32_16x16x32_bf16(af[mi], bfr[ni], accR[mi][ni], 0, 0, 0);
      } else {
        #pragma unroll
        for (int mi = 0; mi < 4; mi++)
          #pragma unroll
          for (int ni = 0; ni < NFR; ni++)
            accL[mi][ni] = __builtin_amdgcn_mfma_f32_16x16x32_bf16(af[mi], bfr[ni], accL[mi][ni], 0, 0, 0);
      }
    }
    // ---- end of t: next buffer must be ready; keep newest stage in flight ----
    if (t + 1 < NT){
      if (t + 2 < NT) wait_vm<LPS>(); else wait_vm<0>();
      __builtin_amdgcn_s_barrier();
    }
  }

  // ---------------- fused epilogue ----------------
  if constexpr (MODE == 0){
    float bb[4];
    #pragma unroll
    for (int ni = 0; ni < 4; ni++) bb[ni] = bias[nbase + wn + ni*16 + l15];
    #pragma unroll
    for (int mi = 0; mi < 4; mi++){
      #pragma unroll
      for (int r = 0; r < 4; r++){
        int node = sbase + mbase + wm + mi*16 + kg*4 + r;
        u16* hp = H + (size_t)node*256 + nbase + wn + l15;
        u16* cp = C + (size_t)node*256 + nbase + wn + l15;
        #pragma unroll
        for (int ni = 0; ni < 4; ni++){
          hp[ni*16] = f2bfu(sigm(accL[mi][ni][r] + bb[ni]));
          cp[ni*16] = 0;
        }
      }
    }
  } else {
    const int eb = blockIdx.y*2 + (wave & 1);
    const int e  = eb*16 + l15;
    float bb[NG];
    #pragma unroll
    for (int g = 0; g < NG; g++) bb[g] = bias[g*256 + e];
    float hss = 0.f, css = 0.f;
    #pragma unroll
    for (int mi = 0; mi < 4; mi++){
      #pragma unroll
      for (int r = 0; r < 4; r++){
        int orow = mbase + wm + mi*16 + kg*4 + r;
        int node = sbase + orow;
        int chl = lidx[node];
        float sl = scH[chl >> 13];
        float cl = bfu2f(Cin[(size_t)chl*256 + e]) * scC[chl >> 13];
        float c2, h2;
        if constexpr (MODE == 1){
          float i_ = sigm(accL[mi][0][r]*sl + bb[0]);
          float f_ = sigm(accL[mi][1][r]*sl + bb[1]);
          float o_ = sigm(accL[mi][2][r]*sl + bb[2]);
          float u_ = tanh_(accL[mi][3][r]*sl + bb[3]);
          c2 = i_*u_ + f_*cl;
          h2 = o_*tanh_(c2);
        } else {
          int chr = ridx[node];
          float sr = scH[chr >> 13];
          float cr = bfu2f(Cin[(size_t)chr*256 + e]) * scC[chr >> 13];
          float g0 = accL[mi][0][r]*sl + accR[mi][0][r]*sr + bb[0];
          float g1 = accL[mi][1][r]*sl + accR[mi][1][r]*sr + bb[1];
          float g2 = accL[mi][2][r]*sl + accR[mi][2][r]*sr + bb[2];
          float g3 = accL[mi][3][r]*sl + accR[mi][3][r]*sr + bb[3];
          float g4 = accL[mi][4][r]*sl + accR[mi][4][r]*sr + bb[4];
          float i_ = sigm(g0);
          float fl = sigm(g1);
          float fr = sigm(g2);
          float o_ = sigm(g3);
          float u_ = tanh_(g4);
          c2 = i_*u_ + fl*cl + fr*cr;
          h2 = o_*tanh_(c2);
        }
        H[(size_t)node*256 + e] = f2bfu(h2);
        C[(size_t)node*256 + e] = f2bfu(c2);
        hss += h2*h2;
        css += c2*c2;
      }
    }
    #pragma unroll
    for (int o = 32; o; o >>= 1){ hss += __shfl_down(hss, o); css += __shfl_down(css, o); }
    if (lane == 0){ red[wave] = hss; red[4+wave] = css; }
    __syncthreads();
    if (tid == 0)  atomicAdd(&sumsq[step],      red[0]+red[1]+red[2]+red[3]);
    if (tid == 64) atomicAdd(&sumsq[16 + step], red[4]+red[5]+red[6]+red[7]);
  }
}

// ---------------------------------------------------------------- output: bf16->f32 with per-step H scale
__global__ __launch_bounds__(256) void out_kernel(
    const u16* __restrict__ H, const float* __restrict__ sumsq, float* __restrict__ out)
{
  size_t base = ((size_t)blockIdx.x*256 + threadIdx.x)*8;
  int n = (int)(base >> 8);
  float s = invs(sumsq[n >> 13]);
  const uint4 v = *reinterpret_cast<const uint4*>(H + base);
  float4 o0, o1;
  o0.x = bfu2f((u16)(v.x & 0xffff))*s; o0.y = bfu2f((u16)(v.x >> 16))*s;
  o0.z = bfu2f((u16)(v.y & 0xffff))*s; o0.w = bfu2f((u16)(v.y >> 16))*s;
  o1.x = bfu2f((u16)(v.z & 0xffff))*s; o1.y = bfu2f((u16)(v.z >> 16))*s;
  o1.z = bfu2f((u16)(v.w & 0xffff))*s; o1.w = bfu2f((u16)(v.w >> 16))*s;
  *reinterpret_cast<float4*>(out + base)     = o0;
  *reinterpret_cast<float4*>(out + base + 4) = o1;
}

// ---------------------------------------------------------------- host
extern "C" void kernel_launch(void* const* d_in, const int* in_sizes, int n_in,
                              void* d_out, int out_size, void* d_ws, size_t ws_size,
                              hipStream_t stream)
{
  const int*   tokens     = (const int*)d_in[0];
  const int*   lidx       = (const int*)d_in[1];
  const int*   ridx       = (const int*)d_in[2];
  const float* leaf_table = (const float*)d_in[6];
  const float* num_W1     = (const float*)d_in[7];
  const float* num_b1     = (const float*)d_in[8];
  const float* num_W2     = (const float*)d_in[9];
  const float* num_b2     = (const float*)d_in[10];
  const float* una_W      = (const float*)d_in[11];
  const float* una_b      = (const float*)d_in[12];
  const float* bin_W      = (const float*)d_in[13];
  const float* bin_b      = (const float*)d_in[14];

  // ws layout: H | wbu | wbb | wbn | h1 | sumsq
  char* ws = (char*)d_ws;
  size_t off = 0;
  u16* H   = (u16*)(ws + off); off += (size_t)N_TOTAL*256*2;
  u16* wbu = (u16*)(ws + off); off += (size_t)2048*256*2;
  u16* wbb = (u16*)(ws + off); off += (size_t)5120*256*2;
  u16* wbn = (u16*)(ws + off); off += (size_t)256*256*2;
  u16* h1  = (u16*)(ws + off); off += (size_t)G_STEP*256*2;
  float* sumsq = (float*)(ws + off); off += 32*4;

  u16* C = (u16*)d_out;  // dead before out_kernel overwrites

  setup_kernel<<<4001, 256, 0, stream>>>(tokens, leaf_table, num_W1, num_b1,
                                         una_W, bin_W, num_W2,
                                         wbu, wbb, wbn, h1, H, C, sumsq);
  gemm_fused<0><<<dim3(64, 2), 256, 0, stream>>>(
      h1, nullptr, nullptr, wbn, num_b2, nullptr, sumsq, H, C, G_STEP, 1);

  const int sched[16] = {-1,-2,0,2,1,3,0,2,1,3,0,2,1,3,0,2};
  for (int d = 2; d < 16; d++){
    int op = sched[d];
    int sbase = d*G_STEP;
    if (op == 0 || op == 1){
      gemm_fused<1><<<dim3(64, 8), 256, 0, stream>>>(
          H, lidx, nullptr, wbu + (size_t)op*1024*256,
          una_b + (size_t)op*4*256, C, sumsq, H, C, sbase, d);
    } else {
      int o2 = op - 2;
      gemm_fused<2><<<dim3(64, 8), 256, 0, stream>>>(
          H, lidx, ridx, wbb + (size_t)o2*2*1280*256,
          bin_b + (size_t)o2*5*256, C, sumsq, H, C, sbase, d);
    }
  }
  out_kernel<<<(N_TOTAL*256)/(256*8), 256, 0, stream>>>(H, sumsq, (float*)d_out);
}